// Round 1
// 408.745 us; speedup vs baseline: 1.0843x; 1.0843x over previous
//
#include <hip/hip_runtime.h>
#include <math.h>

#define T_STEPS 1024
#define BATCH   32
#define DIM     1024
#define NST     64
#define TBN     ((size_t)T_STEPS * BATCH * NST)   // 2M elements per projection

typedef __attribute__((ext_vector_type(8))) short bf16x8;
typedef __attribute__((ext_vector_type(4))) float f32x4;

// ======================= Phase 1: hi/lo bf16 MFMA GEMM, global_load_lds 2-phase =======================
// out[m][n] = sum_d x[m][d]*Wf[n][d], M=32768, fused N=256, K=1024, fp32 in/out.
// x = hi + lo (bf16 truncation split); x.W ~= hi.Whi + lo.Whi + hi.Wlo.
// Tile 128(M) x 256(N) x 32(K), 512 threads = 8 waves as 2(m) x 4(n), wave owns 64x64.
// fp32 staged straight to LDS with global_load_lds (no register round-trip, no cvt on the
// staging path); XOR-swizzle applied on the GLOBAL source address (LDS dest must stay linear)
// and undone on the fragment read -> strided frag reads are bank-balanced (8 acc/bank = b128 min).
// hi/lo split happens on LDS->reg read (each element converted once per consuming wave).
// Grid 256 = 1 block/CU, LDS 96 KB double-buffered. HBM-bound by design (~25-35 us).

__device__ __forceinline__ void gload16(const float* g, float* l)
{
    __builtin_amdgcn_global_load_lds(
        (const __attribute__((address_space(1))) unsigned int*)g,
        (__attribute__((address_space(3))) unsigned int*)l, 16, 0, 0);
}

__device__ __forceinline__ void cvt8(float4 v0, float4 v1, bf16x8& hi, bf16x8& lo)
{
    float f[8] = {v0.x, v0.y, v0.z, v0.w, v1.x, v1.y, v1.z, v1.w};
    bf16x8 h, l;
    #pragma unroll
    for (int i = 0; i < 8; i++) {
        unsigned b = __float_as_uint(f[i]);
        h[i] = (short)(b >> 16);                          // hi = truncate to bf16
        l[i] = (short)(__float_as_uint(f[i] - __uint_as_float(b & 0xffff0000u)) >> 16);
    }
    hi = h; lo = l;
}

__global__ __launch_bounds__(512, 1)
void proj_gemm_v2(const float* __restrict__ x,
                  const float* __restrict__ Wk,
                  const float* __restrict__ Wv,
                  const float* __restrict__ Wq,
                  const float* __restrict__ Wa,
                  const float* __restrict__ b_alpha,
                  float* __restrict__ ws)
{
    __shared__ float As[2][128][32];   // 32 KB
    __shared__ float Bs[2][256][32];   // 64 KB

    const int tid  = threadIdx.x;
    const int lane = tid & 63;
    const int w    = tid >> 6;          // wave 0..7
    const int m0   = blockIdx.x * 128;

    // ---- staging: each wave fills 16 A-rows and 32 B-rows per K-step, 1KB per gload ----
    // lane L covers LDS granule L (16B) of its 1KB chunk: row = 8c + (L>>3), pos = L&7.
    // LDS pos p of row r holds GLOBAL granule p ^ (r&7)  =>  source granule = (L&7)^(L>>3).
    const int lrow  = lane >> 3;            // 0..7 row within 8-row chunk
    const int lgran = (lane & 7) ^ lrow;    // swizzled source granule
    const float* ap0 = x + (size_t)(m0 + 16*w +     lrow) * DIM + lgran * 4;
    const float* ap1 = x + (size_t)(m0 + 16*w + 8 + lrow) * DIM + lgran * 4;
    // wave w stages fused-n rows [32w, 32w+32): all inside one W matrix (w>>1 selects it)
    const float* Wsrc = (w < 2) ? Wk : (w < 4) ? Wv : (w < 6) ? Wq : Wa;
    const float* bp0 = Wsrc + (size_t)((w & 1)*32 +  0 + lrow) * DIM + lgran * 4;
    const float* bp1 = Wsrc + (size_t)((w & 1)*32 +  8 + lrow) * DIM + lgran * 4;
    const float* bp2 = Wsrc + (size_t)((w & 1)*32 + 16 + lrow) * DIM + lgran * 4;
    const float* bp3 = Wsrc + (size_t)((w & 1)*32 + 24 + lrow) * DIM + lgran * 4;

    auto stage = [&](int kb, int buf) {
        const int ko = kb * 32;
        gload16(ap0 + ko, &As[buf][16*w     ][0]);
        gload16(ap1 + ko, &As[buf][16*w +  8][0]);
        gload16(bp0 + ko, &Bs[buf][32*w     ][0]);
        gload16(bp1 + ko, &Bs[buf][32*w +  8][0]);
        gload16(bp2 + ko, &Bs[buf][32*w + 16][0]);
        gload16(bp3 + ko, &Bs[buf][32*w + 24][0]);
    };

    // ---- MFMA fragment ids: lane holds A[m=fr][k=8*qi+j], B[n=fr][k=8*qi+j] ----
    const int fr = lane & 15;
    const int qi = lane >> 4;           // 0..3
    const int sx = fr & 7;              // row swizzle key (row&7 == fr&7 for all frag rows)
    const int mh = w >> 2;              // m-half 0..1
    const int nq = w & 3;               // n-quarter 0..3 == projection selector

    f32x4 acc[4][4];
    #pragma unroll
    for (int i = 0; i < 4; i++)
        #pragma unroll
        for (int j = 0; j < 4; j++)
            acc[i][j] = (f32x4)0.0f;

    stage(0, 0);
    __syncthreads();   // drains vmcnt(0) -> buf0 ready

    #pragma unroll 1
    for (int kb = 0; kb < 32; kb++) {
        const int buf = kb & 1;
        if (kb + 1 < 32) stage(kb + 1, buf ^ 1);   // loads fly under this iter's compute

        bf16x8 ah[4], al[4], bh[4], bl[4];
        #pragma unroll
        for (int mt = 0; mt < 4; mt++) {
            const float* rp = &As[buf][mh*64 + mt*16 + fr][0];
            float4 v0 = *(const float4*)(rp + (((2*qi    ) ^ sx) * 4));
            float4 v1 = *(const float4*)(rp + (((2*qi + 1) ^ sx) * 4));
            cvt8(v0, v1, ah[mt], al[mt]);
        }
        #pragma unroll
        for (int nt = 0; nt < 4; nt++) {
            const float* rp = &Bs[buf][nq*64 + nt*16 + fr][0];
            float4 v0 = *(const float4*)(rp + (((2*qi    ) ^ sx) * 4));
            float4 v1 = *(const float4*)(rp + (((2*qi + 1) ^ sx) * 4));
            cvt8(v0, v1, bh[nt], bl[nt]);
        }
        #pragma unroll
        for (int mt = 0; mt < 4; mt++)
            #pragma unroll
            for (int nt = 0; nt < 4; nt++) {
                acc[mt][nt] = __builtin_amdgcn_mfma_f32_16x16x32_bf16(ah[mt], bh[nt], acc[mt][nt], 0, 0, 0);
                acc[mt][nt] = __builtin_amdgcn_mfma_f32_16x16x32_bf16(al[mt], bh[nt], acc[mt][nt], 0, 0, 0);
                acc[mt][nt] = __builtin_amdgcn_mfma_f32_16x16x32_bf16(ah[mt], bl[nt], acc[mt][nt], 0, 0, 0);
            }

        __syncthreads();   // drains vmcnt (next buf staged) + lgkm (reads done) before reuse
    }

    // epilogue: C/D layout col = lane&15 (n), row = (lane>>4)*4 + reg (m).
    // b_alpha is folded into the ax plane here (same fp32 add the scan used to do).
    float* outb = ws + (size_t)nq * TBN;
    const int r0 = qi * 4;
    float bav[4];
    #pragma unroll
    for (int nt = 0; nt < 4; nt++)
        bav[nt] = (nq == 3) ? b_alpha[nt*16 + fr] : 0.0f;
    #pragma unroll
    for (int mt = 0; mt < 4; mt++)
        #pragma unroll
        for (int nt = 0; nt < 4; nt++)
            #pragma unroll
            for (int r = 0; r < 4; r++)
                outb[(size_t)(m0 + mh*64 + mt*16 + r0 + r) * NST + nt*16 + fr]
                    = acc[mt][nt][r] + bav[nt];
}

// ======================= Phase 2: sequential scan, short-chain form =======================
// ret_{t+1} = a_t*(S_{t-1}.k_{t+1}) + (1-a_t)*v_t*(k_t.k_{t+1}); the k.k dot is S-independent
// so it is hoisted to a per-chunk vector compute (dd[]) -- removes 12 instr + a DPP chain per
// step. All per-step LDS operands are software-pipelined one step ahead. Blocks XCD-swizzled
// so the 16 row-groups of one batch share an XCD L2 (k/q planes fetched once, not 8x).

template <int CTRL>
__device__ __forceinline__ float dpp_add(float v) {
    int o = __builtin_amdgcn_mov_dpp(__float_as_int(v), CTRL, 0xF, 0xF, true);
    return v + __int_as_float(o);
}
__device__ __forceinline__ float reduce16(float v) {
    v = dpp_add<0xB1>(v);     // quad_perm [1,0,3,2]
    v = dpp_add<0x4E>(v);     // quad_perm [2,3,0,1]
    v = dpp_add<0x141>(v);    // ROW_HALF_MIRROR
    v = dpp_add<0x140>(v);    // ROW_MIRROR
    return v;
}
__device__ __forceinline__ float fast_sigmoid(float z) {
    float e = __builtin_amdgcn_exp2f(z * -1.44269504088896340736f);
    return __builtin_amdgcn_rcpf(1.0f + e);
}

#define SCH 16
#define NCH (T_STEPS / SCH)

__global__ __launch_bounds__(64, 1)
void scan16_kernel(const float* __restrict__ ws,
                   const float* __restrict__ S0,
                   const float* __restrict__ d_alpha,
                   float* __restrict__ out)
{
    const float* kb_ = ws;
    const float* vb_ = ws + TBN;
    const float* qb_ = ws + 2 * TBN;
    const float* ab_ = ws + 3 * TBN;   // already has b_alpha folded in

    __shared__ float kq[2][SCH][128];   // [0..63]=k_t, [64..127]=q_t
    __shared__ float va[2][SCH][8];     // [0..3]=v rows, [4..7]=ax rows
    __shared__ float dd[SCH];           // d2[s] = k_s . k_{s+1} for current chunk

    const int lane = threadIdx.x;
    // XCD swizzle: consecutive blockIdx round-robin over 8 XCDs; map so all 16 row-groups
    // of a batch share one XCD class (bid%8 == b>>2) -> k/q L2-resident per XCD (2 MiB < 4 MiB).
    const int bid = blockIdx.x;
    const int b   = (bid & 7) * 4 + ((bid >> 3) & 3);   // batch
    const int rg  = bid >> 5;                           // row group (4 rows)
    const int rl  = lane >> 4;          // 0..3 row within group
    const int cl  = lane & 15;          // column lane
    const int row = rg * 4 + rl;
    const int c0  = cl * 4;

    float S[4];
    {
        float4 sv = *(const float4*)(S0 + ((size_t)b * NST + row) * NST + c0);
        S[0] = sv.x; S[1] = sv.y; S[2] = sv.z; S[3] = sv.w;
    }
    const float da = d_alpha[row];

    const size_t stp = (size_t)BATCH * NST;   // 2048

    // staging maps: kq = 512 float4/chunk, 8 per lane; va = 32 float4, lanes<32
    int kqs[8], kqf[8];
    const float* kqg[8];
    #pragma unroll
    for (int p = 0; p < 8; p++) {
        const int idx = p * 64 + lane;
        const int s   = idx >> 5;
        const int f   = idx & 31;
        kqs[p] = s; kqf[p] = f;
        kqg[p] = ((f < 16) ? kb_ : qb_) + (size_t)s * stp + (size_t)b * NST + (f & 15) * 4;
    }
    const int vas = (lane & 31) >> 1;
    const int vaw = lane & 1;
    const float* vag = (vaw ? ab_ : vb_) + (size_t)vas * stp + (size_t)b * NST + rg * 4;

    auto issue = [&](int ch, float4 (&rk)[8], float4& rv) {
        const size_t off = (size_t)ch * SCH * stp;
        #pragma unroll
        for (int p = 0; p < 8; p++)
            rk[p] = *(const float4*)(kqg[p] + off);
        rv = *(const float4*)(vag + off);
    };
    auto commit = [&](int bi, const float4 (&rk)[8], const float4& rv) {
        #pragma unroll
        for (int p = 0; p < 8; p++)
            *(float4*)&kq[bi][kqs[p]][kqf[p] * 4] = rk[p];
        if (lane < 32)
            *(float4*)&va[bi][vas][vaw * 4] = rv;
    };

    // prologue: chunks 0,1 resident
    {
        float4 rk[8]; float4 rv;
        issue(0, rk, rv); commit(0, rk, rv);
        issue(1, rk, rv); commit(1, rk, rv);
    }

    // pipeline registers: kc = k_t, kn = k_{t+1}; step-0 operands of chunk 0
    float kc[4], kn[4];
    *(float4*)kc = *(const float4*)&kq[0][0][c0];
    *(float4*)kn = *(const float4*)&kq[0][1][c0];
    float qf_c[4];
    *(float4*)qf_c = *(const float4*)&kq[0][0][64 + c0];
    float vv_c = va[0][0][rl];
    float aa_c = va[0][0][4 + rl];

    // ret_0 = S0 . k_0
    float ret;
    {
        float p0 = fmaf(S[1], kc[1], S[0] * kc[0]) + fmaf(S[3], kc[3], S[2] * kc[2]);
        ret = reduce16(p0);
    }

    float* op = out + (size_t)b * NST + row;

    for (int ch = 0; ch < NCH; ch++) {
        const int cur = ch & 1, nxt = cur ^ 1;

        float4 rk[8]; float4 rv;
        const int cn = (ch + 2 < NCH) ? ch + 2 : NCH - 1;
        issue(cn, rk, rv);   // global loads fly under the chunk's compute

        // ---- per-chunk d2 vector: dd[tl] = k_{ch*16+tl} . k_{ch*16+tl+1} ----
        // lane = (tl = lane&15 step, qg = lane>>4 col-quarter); granule order rotated by tl
        // so the 16 same-column rows don't collide on banks (balanced 8 acc/bank).
        {
            const int tl = lane & 15;
            const int qg = lane >> 4;
            const float* kt = &kq[cur][tl][0];
            const float* knp = (tl < 15) ? &kq[cur][tl + 1][0] : &kq[nxt][0][0];
            float dsum = 0.0f;
            #pragma unroll
            for (int i = 0; i < 4; i++) {
                const int g = ((qg * 4 + i + tl) & 15) * 4;
                float4 a = *(const float4*)(kt + g);
                float4 c = *(const float4*)(knp + g);
                dsum = fmaf(a.x, c.x, dsum); dsum = fmaf(a.y, c.y, dsum);
                dsum = fmaf(a.z, c.z, dsum); dsum = fmaf(a.w, c.w, dsum);
            }
            dsum += __shfl_xor(dsum, 16);
            dsum += __shfl_xor(dsum, 32);
            if (lane < 16) dd[lane] = dsum;
        }

        #pragma unroll
        for (int s = 0; s < SCH; s++) {
            const int t = ch * SCH + s;

            // ---- prefetch step s+1 operands (latency hides under this step) ----
            float qf_n[4], kn2[4], vv_n, aa_n;
            if (s < SCH - 1) {
                *(float4*)qf_n = *(const float4*)&kq[cur][s + 1][64 + c0];
                vv_n = va[cur][s + 1][rl];
                aa_n = va[cur][s + 1][4 + rl];
            } else {
                *(float4*)qf_n = *(const float4*)&kq[nxt][0][64 + c0];
                vv_n = va[nxt][0][rl];
                aa_n = va[nxt][0][4 + rl];
            }
            if (s < SCH - 2)       *(float4*)kn2 = *(const float4*)&kq[cur][s + 2][c0];
            else if (s == SCH - 2) *(float4*)kn2 = *(const float4*)&kq[nxt][0][c0];
            else                   *(float4*)kn2 = *(const float4*)&kq[nxt][1][c0];

            const float d2v = dd[s];   // broadcast read

            // --- recurrence chain: fma -> sigmoid ---
            const float z     = fmaf(da, ret, aa_c);
            const float alpha = fast_sigmoid(z);

            // --- shadow dot (old S, preloaded k_{t+1}) ---
            float d1 = fmaf(S[1], kn[1], S[0] * kn[0]) + fmaf(S[3], kn[3], S[2] * kn[2]);
            d1 = reduce16(d1);                 // S_{t-1} . k_{t+1}

            // --- S update ---
            const float w = (1.f - alpha) * vv_c;
            S[0] = fmaf(alpha, S[0], w * kc[0]);
            S[1] = fmaf(alpha, S[1], w * kc[1]);
            S[2] = fmaf(alpha, S[2], w * kc[2]);
            S[3] = fmaf(alpha, S[3], w * kc[3]);

            // --- next ret (one fma after alpha) ---
            const float c2v = vv_c * d2v;
            ret = fmaf(alpha, d1 - c2v, c2v);

            // --- output ---
            float h = fmaf(S[1], qf_c[1], S[0] * qf_c[0]) + fmaf(S[3], qf_c[3], S[2] * qf_c[2]);
            h = reduce16(h);
            const float o = h * h * fast_sigmoid(h);   // h * silu(h)
            if (cl == 0) op[(size_t)t * stp] = o;

            // --- rotate pipeline ---
            kc[0] = kn[0]; kc[1] = kn[1]; kc[2] = kn[2]; kc[3] = kn[3];
            kn[0] = kn2[0]; kn[1] = kn2[1]; kn[2] = kn2[2]; kn[3] = kn2[3];
            qf_c[0] = qf_n[0]; qf_c[1] = qf_n[1]; qf_c[2] = qf_n[2]; qf_c[3] = qf_n[3];
            vv_c = vv_n; aa_c = aa_n;
        }

        commit(cur, rk, rv);   // chunk ch+2 into the buffer chunk ch vacated
    }

    // S_final
    float* sfp = out + TBN + ((size_t)b * NST + row) * NST + c0;
    *(float4*)sfp = make_float4(S[0], S[1], S[2], S[3]);
}

// ======================= launch =======================

extern "C" void kernel_launch(void* const* d_in, const int* in_sizes, int n_in,
                              void* d_out, int out_size, void* d_ws, size_t ws_size,
                              hipStream_t stream)
{
    const float* x  = (const float*)d_in[0];
    const float* S0 = (const float*)d_in[1];
    const float* Wk = (const float*)d_in[2];
    const float* Wv = (const float*)d_in[3];
    const float* Wq = (const float*)d_in[4];
    const float* Wa = (const float*)d_in[5];
    const float* da = (const float*)d_in[6];
    const float* ba = (const float*)d_in[7];
    float* out = (float*)d_out;
    float* ws  = (float*)d_ws;   // 4 x [T,B,N] fp32 = 32 MiB (unchanged layout)

    proj_gemm_v2<<<dim3((T_STEPS * BATCH) / 128), 512, 0, stream>>>(x, Wk, Wv, Wq, Wa, ba, ws);

    scan16_kernel<<<dim3(BATCH * 16), 64, 0, stream>>>(ws, S0, da, out);
}